// Round 5
// baseline (1171.038 us; speedup 1.0000x reference)
//
#include <hip/hip_runtime.h>
#include <stdint.h>
#include <math.h>

#define T_SIM 500
#define NB    64
#define NIN   1024
#define NHID  1024
#define NOUT  10
#define KSRM  77     // SRM kernel taps 0..76 (srm[0] == 0)
#define CHUNK 32     // batches per chunk for layer-1 pipeline
#define TT2   36     // t-tile in fused psp+spike kernel (192 FIR thr x 6 out)
#define NT    14     // ceil(500/36); last tile tv=32
#define RING2 148    // ring rows: 112 live + 36 incoming, span 147 < 148

// Reference builds kernels in python f64 then rounds to fp32; we reproduce the
// exact fp32 tap values and do all accumulation in f64 (verified: absmax 0).
__device__ __forceinline__ double srm_tap(int k) {
  double u = (double)k / 10.0;
  double v = u * exp(1.0 - u);
  return (double)(float)v;
}
__device__ __forceinline__ double ref_tap(int j) {
  double v = (-20.0 * (double)j) * exp(1.0 - (double)j);
  return (double)(float)v;
}

// ---------------------------------------------------------------------------
// K0: pack binary input spikes x[b][i][t] (fp32 0/1) -> bits [b][t][16 x u64]
__global__ __launch_bounds__(64)
void k_pack(const float* __restrict__ x, unsigned long long* __restrict__ bits) {
  const int b = blockIdx.x, ig = blockIdx.y, tc = blockIdx.z;
  const int lane = threadIdx.x;
  const float* xr = x + ((size_t)b * NIN + ig * 64 + lane) * T_SIM;
  const int t0 = tc * 100;
  for (int t = t0; t < t0 + 100; t += 4) {
    const float4 v = *(const float4*)(xr + t);
    unsigned long long m0 = __ballot(v.x > 0.5f);
    unsigned long long m1 = __ballot(v.y > 0.5f);
    unsigned long long m2 = __ballot(v.z > 0.5f);
    unsigned long long m3 = __ballot(v.w > 0.5f);
    if (lane == 0) {
      unsigned long long* w = bits + (size_t)(b * T_SIM + t) * 16 + ig;
      w[0] = m0; w[16] = m1; w[32] = m2; w[48] = m3;
    }
  }
}

// ---------------------------------------------------------------------------
// K0b: W1[o][i] -> W1T[i][o] fp32, tiled 64x64 through LDS.
__global__ __launch_bounds__(256)
void k_transpose(const float* __restrict__ W1, float* __restrict__ W1T) {
  __shared__ float tile[64][65];
  const int bo = blockIdx.x * 64, bi = blockIdx.y * 64;
  for (int k = threadIdx.x; k < 4096; k += 256) {
    int r = k >> 6, c = k & 63;
    tile[r][c] = W1[(size_t)(bo + r) * NIN + bi + c];
  }
  __syncthreads();
  for (int k = threadIdx.x; k < 4096; k += 256) {
    int r = k >> 6, c = k & 63;
    W1T[(size_t)(bi + r) * NHID + bo + c] = tile[c][r];
  }
}

// ---------------------------------------------------------------------------
// K1: dense1 sparse gather, f64 acc, 2-stage load pipeline. Numerics are
// bitwise-identical to R4 (element g -> acc set g&3, same merge order).
__global__ __launch_bounds__(256)
void k_dense1(const uint32_t* __restrict__ bits, const float* __restrict__ W1T,
              double* __restrict__ a1c, int col_base) {
  __shared__ int list[NIN];
  __shared__ int nact_s;
  const int col_loc = blockIdx.x;
  const int tid = threadIdx.x;
  if (tid < 32) {
    uint32_t w = bits[(size_t)(col_base + col_loc) * 32 + tid];
    int c = __popc(w);
    int p = c;
#pragma unroll
    for (int d = 1; d < 32; d <<= 1) {
      int q = __shfl_up(p, d);
      if (tid >= d) p += q;
    }
    int excl = p - c;
    while (w) {
      const int j = __ffs(w) - 1;
      w &= w - 1;
      list[excl++] = tid * 32 + j;   // i ascending overall
    }
    if (tid == 31) nact_s = excl;
  }
  __syncthreads();
  const int n = nact_s;
  const int o = tid * 4;
  double a0x=0,a0y=0,a0z=0,a0w=0, a1x=0,a1y=0,a1z=0,a1w=0;
  double a2x=0,a2y=0,a2z=0,a2w=0, a3x=0,a3y=0,a3z=0,a3w=0;
  float4 L0, L1, L2, L3;
  int g = 0;
  if (g + 4 <= n) {
    L0 = *(const float4*)(W1T + (size_t)list[0] * NHID + o);
    L1 = *(const float4*)(W1T + (size_t)list[1] * NHID + o);
    L2 = *(const float4*)(W1T + (size_t)list[2] * NHID + o);
    L3 = *(const float4*)(W1T + (size_t)list[3] * NHID + o);
  }
  for (; g + 4 <= n; g += 4) {
    float4 N0, N1, N2, N3;
    const bool more = (g + 8 <= n);
    if (more) {
      N0 = *(const float4*)(W1T + (size_t)list[g+4] * NHID + o);
      N1 = *(const float4*)(W1T + (size_t)list[g+5] * NHID + o);
      N2 = *(const float4*)(W1T + (size_t)list[g+6] * NHID + o);
      N3 = *(const float4*)(W1T + (size_t)list[g+7] * NHID + o);
    }
    a0x += (double)L0.x; a0y += (double)L0.y; a0z += (double)L0.z; a0w += (double)L0.w;
    a1x += (double)L1.x; a1y += (double)L1.y; a1z += (double)L1.z; a1w += (double)L1.w;
    a2x += (double)L2.x; a2y += (double)L2.y; a2z += (double)L2.z; a2w += (double)L2.w;
    a3x += (double)L3.x; a3y += (double)L3.y; a3z += (double)L3.z; a3w += (double)L3.w;
    if (more) { L0 = N0; L1 = N1; L2 = N2; L3 = N3; }
  }
  if (g + 0 < n) {
    const float4 wv = *(const float4*)(W1T + (size_t)list[g+0] * NHID + o);
    a0x += (double)wv.x; a0y += (double)wv.y; a0z += (double)wv.z; a0w += (double)wv.w;
  }
  if (g + 1 < n) {
    const float4 wv = *(const float4*)(W1T + (size_t)list[g+1] * NHID + o);
    a1x += (double)wv.x; a1y += (double)wv.y; a1z += (double)wv.z; a1w += (double)wv.w;
  }
  if (g + 2 < n) {
    const float4 wv = *(const float4*)(W1T + (size_t)list[g+2] * NHID + o);
    a2x += (double)wv.x; a2y += (double)wv.y; a2z += (double)wv.z; a2w += (double)wv.w;
  }
  double4 r;
  r.x = (a0x + a1x) + (a2x + a3x);
  r.y = (a0y + a1y) + (a2y + a3y);
  r.z = (a0z + a1z) + (a2z + a3z);
  r.w = (a0w + a1w) + (a2w + a3w);
  *(double4*)(a1c + (size_t)col_loc * NHID + o) = r;
}

// ---------------------------------------------------------------------------
// K2: FUSED psp1 + spike1 v3. Waves 1..3 (192 thr): FIR, 6 outputs/thread via
// rotation-unrolled taps (no movs, 2 LDS reads per 6 f64 FMA). Wave 0: scans
// tile k-1 concurrently (Y double-buffered). One barrier per tile.
// grid (32, CHUNK), block 256. LDS: 148*32*8 + 2*36*32*8 + 87*8 = 57,016 B.
__global__ __launch_bounds__(256)
void k_ps1(const double* __restrict__ a1c, uint32_t* __restrict__ s1w,
           int b_base) {
  __shared__ double S[RING2 * 32];
  __shared__ double Y[2][TT2 * 32];
  __shared__ double TB[87];   // TB[e] = srm[e-5] for 5<=e<=81, else 0
  const int ng = blockIdx.x, b_loc = blockIdx.y;
  const int tid = threadIdx.x;

  const double* __restrict__ abase = a1c + (size_t)b_loc * T_SIM * NHID + ng * 32;
  uint32_t* __restrict__ sbase = s1w + (size_t)(b_base + b_loc) * T_SIM * 32 + ng;

  if (tid < 87) {
    double v = 0.0;
    if (tid >= 5 && tid <= 81) v = srm_tap(tid - 5);
    TB[tid] = v;
  }
  for (int i = tid; i < RING2 * 32; i += 256) S[i] = 0.0;
  __syncthreads();
  // load tile 0 (slots 0..35, no wrap)
  for (int id = tid; id < TT2 * 32; id += 256) {
    const int r = id >> 5, nn = id & 31;
    S[r * 32 + nn] = abase[(size_t)r * NHID + nn];
  }
  __syncthreads();

  double refk[11];
#pragma unroll
  for (int j = 1; j <= 10; ++j) refk[j] = ref_tap(j);
  uint32_t smask = 0;

  for (int k = 0; k < NT; ++k) {
    const int t0 = k * TT2;
    const int tv = (T_SIM - t0 < TT2) ? (T_SIM - t0) : TT2;
    const int t0n = t0 + TT2;
    const int tvn = (t0n >= T_SIM) ? 0 : ((T_SIM - t0n < TT2) ? (T_SIM - t0n) : TT2);
    if (tid >= 64) {
      const int f = tid - 64;
      // ---- prefetch tile k+1 (slots provably disjoint from window k) ----
      double pf[6];
#pragma unroll
      for (int j = 0; j < 6; ++j) {
        const int id = f + j * 192;
        if (id < tvn * 32) {
          const int r = id >> 5, nn = id & 31;
          pf[j] = abase[(size_t)(t0n + r) * NHID + nn];
        }
      }
      // ---- FIR tile k: outputs tb..tb+5, inputs tb-76..tb+5 (s=0..81) ----
      const int n = f & 31, tq = f >> 5;
      const int tb = t0 + tq * 6;
      int m0 = (tb - 76) % RING2; if (m0 < 0) m0 += RING2;
      double acc[6] = {0, 0, 0, 0, 0, 0};
      double tr[6];
#pragma unroll
      for (int e = 81; e <= 86; ++e) tr[e % 6] = TB[e];  // taps for s=0
      int idx = m0;
      for (int sb = 0; sb < 78; sb += 6) {
#pragma unroll
        for (int r = 0; r < 6; ++r) {
          const int s = sb + r;
          const double v = S[idx * 32 + n];
          idx = (idx + 1 == RING2) ? 0 : idx + 1;
#pragma unroll
          for (int u = 0; u < 6; ++u)
            acc[u] += tr[(9 - r + u) % 6] * v;    // tap e = 81-s+u
          tr[(8 - r) % 6] = TB[80 - s];           // tap for s+1 (e = 80-s >= 3)
        }
      }
#pragma unroll
      for (int r = 0; r < 4; ++r) {               // tail s = 78..81 (s%6 == r)
        const int s = 78 + r;
        const double v = S[idx * 32 + n];
        idx = (idx + 1 == RING2) ? 0 : idx + 1;
#pragma unroll
        for (int u = 0; u < 6; ++u)
          acc[u] += tr[(9 - r + u) % 6] * v;      // e = 3-r+u >= 0 ✓
        if (r < 3) tr[(8 - r) % 6] = TB[80 - s];  // e = 2..0 (zeros)
      }
      const int tl0 = tq * 6;
      double* Yk = Y[k & 1];
#pragma unroll
      for (int u = 0; u < 6; ++u)
        if (tl0 + u < tv) Yk[(tl0 + u) * 32 + n] = acc[u];
      // ---- write prefetched tile k+1 into ring ----
#pragma unroll
      for (int j = 0; j < 6; ++j) {
        const int id = f + j * 192;
        if (id < tvn * 32) {
          const int r = id >> 5, nn = id & 31;
          S[((t0n + r) % RING2) * 32 + nn] = pf[j];
        }
      }
    } else if (k > 0) {
      // ---- wave 0: refractory scan of tile k-1 (always tv=36 here) ----
      if (tid < 32) {
        const int t0p = (k - 1) * TT2;
        const double* Yp = Y[(k - 1) & 1];
        for (int g = 0; g < TT2; ++g) {
          double u = Yp[g * 32 + tid];
#pragma unroll
          for (int j = 10; j >= 1; --j)
            u += refk[j] * (double)((smask >> (j - 1)) & 1u);
          const bool sp = (u >= 10.0);
          smask = (smask << 1) | (sp ? 1u : 0u);
          const unsigned long long bm = __ballot(sp);
          if (tid == 0) sbase[(size_t)(t0p + g) * 32] = (uint32_t)bm;
        }
      }
    }
    __syncthreads();
  }
  // epilogue: scan last tile (tv = 32)
  if (tid < 32) {
    const int t0p = (NT - 1) * TT2;
    const int tvp = T_SIM - t0p;
    const double* Yp = Y[(NT - 1) & 1];
    for (int g = 0; g < tvp; ++g) {
      double u = Yp[g * 32 + tid];
#pragma unroll
      for (int j = 10; j >= 1; --j)
        u += refk[j] * (double)((smask >> (j - 1)) & 1u);
      const bool sp = (u >= 10.0);
      smask = (smask << 1) | (sp ? 1u : 0u);
      const unsigned long long bm = __ballot(sp);
      if (tid == 0) sbase[(size_t)(t0p + g) * 32] = (uint32_t)bm;
    }
  }
}

// ---------------------------------------------------------------------------
// K3: dense2 sparse gather from s1 u32 masks, W2 fp32 in LDS, f64 acc.
__global__ __launch_bounds__(256)
void k_dense2(const uint32_t* __restrict__ s1w,
              const float* __restrict__ W2, double* __restrict__ a2) {
  __shared__ float w2t[NHID * NOUT];  // 40 KB, [i][o]
  for (int k = threadIdx.x; k < NHID * NOUT; k += 256) {
    const int o = k >> 10, i = k & 1023;
    w2t[i * NOUT + o] = W2[k];
  }
  __syncthreads();
  const int col = blockIdx.x * 256 + threadIdx.x;  // 0..31999
  double acc[NOUT];
#pragma unroll
  for (int o = 0; o < NOUT; ++o) acc[o] = 0.0;
  const uint32_t* w = s1w + (size_t)col * 32;
  for (int wi = 0; wi < 32; ++wi) {
    uint32_t m = w[wi];
    const int ibase = wi * 32;
    while (m) {
      const int j = __ffs(m) - 1;
      m &= m - 1;
      const float* row = &w2t[(ibase + j) * NOUT];
#pragma unroll
      for (int o = 0; o < NOUT; ++o) acc[o] += (double)row[o];
    }
  }
  double* outp = a2 + (size_t)col * NOUT;
#pragma unroll
  for (int o = 0; o < NOUT; ++o) outp[o] = acc[o];
}

// ---------------------------------------------------------------------------
// K4: FUSED psp2 + spike2, one block per batch; whole [500][10] in LDS.
__global__ __launch_bounds__(256)
void k_l2(const double* __restrict__ a2, float* __restrict__ out) {
  __shared__ double S[T_SIM * NOUT];
  __shared__ double Y[T_SIM * NOUT];
  __shared__ double srm[KSRM];
  const int b = blockIdx.x, tid = threadIdx.x;
  if (tid < KSRM) srm[tid] = srm_tap(tid);
  for (int i = tid; i < T_SIM * NOUT; i += 256)
    S[i] = a2[(size_t)b * T_SIM * NOUT + i];
  __syncthreads();
  for (int i = tid; i < T_SIM * NOUT; i += 256) {
    const int t = i / 10, o = i - t * 10;
    const int kmax = (t < KSRM - 1) ? t : (KSRM - 1);
    double acc = 0.0;
    for (int k = 0; k <= kmax; ++k)
      acc += srm[k] * S[(t - k) * 10 + o];
    Y[i] = acc;
  }
  __syncthreads();
  if (tid < NOUT) {
    double refk[11];
#pragma unroll
    for (int j = 1; j <= 10; ++j) refk[j] = ref_tap(j);
    uint32_t smask = 0;
    float* op = out + ((size_t)b * NOUT + tid) * T_SIM;
    for (int t = 0; t < T_SIM; ++t) {
      double u = Y[t * 10 + tid];
#pragma unroll
      for (int j = 10; j >= 1; --j)
        u += refk[j] * (double)((smask >> (j - 1)) & 1u);
      const bool sp = (u >= 10.0);
      smask = (smask << 1) | (sp ? 1u : 0u);
      op[t] = sp ? 1.0f : 0.0f;
    }
  }
}

// ---------------------------------------------------------------------------
extern "C" void kernel_launch(void* const* d_in, const int* in_sizes, int n_in,
                              void* d_out, int out_size, void* d_ws, size_t ws_size,
                              hipStream_t stream) {
  const float* x  = (const float*)d_in[0];   // [64][1024][500]
  const float* W1 = (const float*)d_in[1];   // [1024][1024]
  const float* W2 = (const float*)d_in[2];   // [10][1024]
  float* out = (float*)d_out;                // [64][10][500]

  char* ws = (char*)d_ws;
  unsigned long long* bits1 = (unsigned long long*)(ws);   // 4,096,000
  float*  W1T = (float*) (ws + 4096000);                   // 4,194,304
  double* a1c = (double*)(ws + 8290304);                   // 131,072,000 (CHUNK=32)
  uint32_t* s1w = (uint32_t*)(ws + 139362304);             // 4,096,000
  double* a2  = (double*)(ws + 143458304);                 // 2,560,000
  // total ws use: 146,018,304 B

  hipLaunchKernelGGL(k_pack, dim3(NB, 16, 5), dim3(64), 0, stream, x, bits1);
  hipLaunchKernelGGL(k_transpose, dim3(16, 16), dim3(256), 0, stream, W1, W1T);

  for (int bc = 0; bc < NB; bc += CHUNK) {
    hipLaunchKernelGGL(k_dense1, dim3(CHUNK * T_SIM), dim3(256), 0, stream,
                       (const uint32_t*)bits1, W1T, a1c, bc * T_SIM);
    hipLaunchKernelGGL(k_ps1, dim3(32, CHUNK), dim3(256), 0, stream,
                       a1c, s1w, bc);
  }

  hipLaunchKernelGGL(k_dense2, dim3(125), dim3(256), 0, stream, s1w, W2, a2);
  hipLaunchKernelGGL(k_l2, dim3(NB), dim3(256), 0, stream, a2, out);
}

// Round 6
// 1012.427 us; speedup vs baseline: 1.1567x; 1.1567x over previous
//
#include <hip/hip_runtime.h>
#include <stdint.h>
#include <math.h>

#define T_SIM 500
#define NB    64
#define NIN   1024
#define NHID  1024
#define NOUT  10
#define KSRM  77     // SRM kernel taps 0..76 (srm[0] == 0)
#define CHUNK 32     // batches per chunk for layer-1 pipeline
#define TT3   16     // t-tile in fused psp+spike kernel
#define NT3   32     // ceil(500/16); last tile tv=4
#define RING3 108    // 76 history + 2*TT3

// Reference builds kernels in python f64 then rounds to fp32; we reproduce the
// exact fp32 tap values and do all accumulation in f64 (verified: absmax 0).
__device__ __forceinline__ double srm_tap(int k) {
  double u = (double)k / 10.0;
  double v = u * exp(1.0 - u);
  return (double)(float)v;
}
__device__ __forceinline__ double ref_tap(int j) {
  double v = (-20.0 * (double)j) * exp(1.0 - (double)j);
  return (double)(float)v;
}

// ---------------------------------------------------------------------------
// K0: pack binary input spikes x[b][i][t] (fp32 0/1) -> bits [b][t][16 x u64]
__global__ __launch_bounds__(64)
void k_pack(const float* __restrict__ x, unsigned long long* __restrict__ bits) {
  const int b = blockIdx.x, ig = blockIdx.y, tc = blockIdx.z;
  const int lane = threadIdx.x;
  const float* xr = x + ((size_t)b * NIN + ig * 64 + lane) * T_SIM;
  const int t0 = tc * 100;
  for (int t = t0; t < t0 + 100; t += 4) {
    const float4 v = *(const float4*)(xr + t);
    unsigned long long m0 = __ballot(v.x > 0.5f);
    unsigned long long m1 = __ballot(v.y > 0.5f);
    unsigned long long m2 = __ballot(v.z > 0.5f);
    unsigned long long m3 = __ballot(v.w > 0.5f);
    if (lane == 0) {
      unsigned long long* w = bits + (size_t)(b * T_SIM + t) * 16 + ig;
      w[0] = m0; w[16] = m1; w[32] = m2; w[48] = m3;
    }
  }
}

// ---------------------------------------------------------------------------
// K0b: W1[o][i] -> W1T[i][o] fp32, tiled 64x64 through LDS.
__global__ __launch_bounds__(256)
void k_transpose(const float* __restrict__ W1, float* __restrict__ W1T) {
  __shared__ float tile[64][65];
  const int bo = blockIdx.x * 64, bi = blockIdx.y * 64;
  for (int k = threadIdx.x; k < 4096; k += 256) {
    int r = k >> 6, c = k & 63;
    tile[r][c] = W1[(size_t)(bo + r) * NIN + bi + c];
  }
  __syncthreads();
  for (int k = threadIdx.x; k < 4096; k += 256) {
    int r = k >> 6, c = k & 63;
    W1T[(size_t)(bi + r) * NHID + bo + c] = tile[c][r];
  }
}

// ---------------------------------------------------------------------------
// K1: dense1 sparse gather, f64 acc, 2-stage load pipeline. Per-o numerics
// bitwise-identical to R4/R5 (element g -> acc set g&3, same merge order).
// grid (CHUNK*500, 2), block 128: o-half per block for 2x parallelism.
__global__ __launch_bounds__(128)
void k_dense1(const uint32_t* __restrict__ bits, const float* __restrict__ W1T,
              double* __restrict__ a1c, int col_base) {
  __shared__ int list[NIN];
  __shared__ int nact_s;
  const int col_loc = blockIdx.x;
  const int tid = threadIdx.x;
  if (tid < 32) {
    uint32_t w = bits[(size_t)(col_base + col_loc) * 32 + tid];
    int c = __popc(w);
    int p = c;
#pragma unroll
    for (int d = 1; d < 32; d <<= 1) {
      int q = __shfl_up(p, d);
      if (tid >= d) p += q;
    }
    int excl = p - c;
    while (w) {
      const int j = __ffs(w) - 1;
      w &= w - 1;
      list[excl++] = tid * 32 + j;   // i ascending overall
    }
    if (tid == 31) nact_s = excl;
  }
  __syncthreads();
  const int n = nact_s;
  const int o = blockIdx.y * 512 + tid * 4;
  double a0x=0,a0y=0,a0z=0,a0w=0, a1x=0,a1y=0,a1z=0,a1w=0;
  double a2x=0,a2y=0,a2z=0,a2w=0, a3x=0,a3y=0,a3z=0,a3w=0;
  float4 L0, L1, L2, L3;
  int g = 0;
  if (g + 4 <= n) {
    L0 = *(const float4*)(W1T + (size_t)list[0] * NHID + o);
    L1 = *(const float4*)(W1T + (size_t)list[1] * NHID + o);
    L2 = *(const float4*)(W1T + (size_t)list[2] * NHID + o);
    L3 = *(const float4*)(W1T + (size_t)list[3] * NHID + o);
  }
  for (; g + 4 <= n; g += 4) {
    float4 N0, N1, N2, N3;
    const bool more = (g + 8 <= n);
    if (more) {
      N0 = *(const float4*)(W1T + (size_t)list[g+4] * NHID + o);
      N1 = *(const float4*)(W1T + (size_t)list[g+5] * NHID + o);
      N2 = *(const float4*)(W1T + (size_t)list[g+6] * NHID + o);
      N3 = *(const float4*)(W1T + (size_t)list[g+7] * NHID + o);
    }
    a0x += (double)L0.x; a0y += (double)L0.y; a0z += (double)L0.z; a0w += (double)L0.w;
    a1x += (double)L1.x; a1y += (double)L1.y; a1z += (double)L1.z; a1w += (double)L1.w;
    a2x += (double)L2.x; a2y += (double)L2.y; a2z += (double)L2.z; a2w += (double)L2.w;
    a3x += (double)L3.x; a3y += (double)L3.y; a3z += (double)L3.z; a3w += (double)L3.w;
    if (more) { L0 = N0; L1 = N1; L2 = N2; L3 = N3; }
  }
  if (g + 0 < n) {
    const float4 wv = *(const float4*)(W1T + (size_t)list[g+0] * NHID + o);
    a0x += (double)wv.x; a0y += (double)wv.y; a0z += (double)wv.z; a0w += (double)wv.w;
  }
  if (g + 1 < n) {
    const float4 wv = *(const float4*)(W1T + (size_t)list[g+1] * NHID + o);
    a1x += (double)wv.x; a1y += (double)wv.y; a1z += (double)wv.z; a1w += (double)wv.w;
  }
  if (g + 2 < n) {
    const float4 wv = *(const float4*)(W1T + (size_t)list[g+2] * NHID + o);
    a2x += (double)wv.x; a2y += (double)wv.y; a2z += (double)wv.z; a2w += (double)wv.w;
  }
  double4 r;
  r.x = (a0x + a1x) + (a2x + a3x);
  r.y = (a0y + a1y) + (a2y + a3y);
  r.z = (a0z + a1z) + (a2z + a3z);
  r.w = (a0w + a1w) + (a2w + a3w);
  *(double4*)(a1c + (size_t)col_loc * NHID + o) = r;
}

// ---------------------------------------------------------------------------
// K2: FUSED psp1 + spike1 v4 — tap-split FIR. 512 thr = 4 tap-groups x 4
// t-quads x 32 n. Each thread holds 20 taps in REGISTERS (static index after
// unroll) and computes a partial FIR for 4 outputs; scan sums the 4 partials.
// Scan (lanes 0..31) overlaps next tile's ring load (tid>=64). 2 barriers/tile.
// grid (32, CHUNK). LDS: 108*32*8 + 4*16*32*8 + 80*8 = 44,672 B -> 3 blk/CU.
__global__ __launch_bounds__(512)
void k_ps1(const double* __restrict__ a1c, uint32_t* __restrict__ s1w,
           int b_base) {
  __shared__ double S[RING3 * 32];
  __shared__ double Y[4][TT3 * 32];
  __shared__ double TB[80];     // srm[0..76], zero-padded to 80
  const int ng = blockIdx.x, b_loc = blockIdx.y;
  const int tid = threadIdx.x;

  const double* __restrict__ abase = a1c + (size_t)b_loc * T_SIM * NHID + ng * 32;
  uint32_t* __restrict__ sbase = s1w + (size_t)(b_base + b_loc) * T_SIM * 32 + ng;

  if (tid < 80) TB[tid] = (tid <= 76) ? srm_tap(tid) : 0.0;
  for (int i = tid; i < RING3 * 32; i += 512) S[i] = 0.0;
  __syncthreads();
  // load tile 0 (slots 0..15)
  for (int id = tid; id < TT3 * 32; id += 512) {
    const int r = id >> 5, nn = id & 31;
    S[r * 32 + nn] = abase[(size_t)r * NHID + nn];
  }

  const int g  = tid >> 7;          // tap group 0..3 (taps 20g..20g+19)
  const int tq = (tid >> 5) & 3;    // t-quad 0..3
  const int n  = tid & 31;          // neuron
  double tap[20];
  __syncthreads();                  // TB + tile0 ready
#pragma unroll
  for (int j = 0; j < 20; ++j) tap[j] = TB[20 * g + j];  // 20g+19 <= 79 ✓

  double refk[11];
#pragma unroll
  for (int j = 1; j <= 10; ++j) refk[j] = ref_tap(j);
  uint32_t smask = 0;

  for (int k = 0; k < NT3; ++k) {
    const int t0 = k * TT3;
    const int tv = (T_SIM - t0 < TT3) ? (T_SIM - t0) : TT3;
    // ---- partial FIR: outputs tb..tb+3, taps k=20g..20g+19 ----
    {
      const int tb = t0 + tq * 4;
      int slot = tb - 20 * g - 19;
      slot %= RING3; if (slot < 0) slot += RING3;
      double a0 = 0, a1 = 0, a2 = 0, a3 = 0;
#pragma unroll
      for (int s = 0; s < 23; ++s) {
        const double v = S[slot * 32 + n];
        slot = (slot + 1 == RING3) ? 0 : slot + 1;
        // j = u + 19 - s (static); tap index always in [0,19]
        if (s <= 19)            a0 += tap[19 - s] * v;
        if (s >= 1 && s <= 20)  a1 += tap[20 - s] * v;
        if (s >= 2 && s <= 21)  a2 += tap[21 - s] * v;
        if (s >= 3)             a3 += tap[22 - s] * v;
      }
      double* Yg = Y[g];
      const int tl = tq * 4;
      Yg[(tl + 0) * 32 + n] = a0;
      Yg[(tl + 1) * 32 + n] = a1;
      Yg[(tl + 2) * 32 + n] = a2;
      Yg[(tl + 3) * 32 + n] = a3;
    }
    __syncthreads();
    // ---- scan(k) on lanes 0..31  ||  ring load of tile k+1 on tid>=64 ----
    const int t0n = t0 + TT3;
    const int tvn = (t0n >= T_SIM) ? 0 : ((T_SIM - t0n < TT3) ? (T_SIM - t0n) : TT3);
    if (tid < 32) {
      for (int gg = 0; gg < tv; ++gg) {
        double u = (Y[0][gg * 32 + tid] + Y[1][gg * 32 + tid]) +
                   (Y[2][gg * 32 + tid] + Y[3][gg * 32 + tid]);
#pragma unroll
        for (int j = 10; j >= 1; --j)
          u += refk[j] * (double)((smask >> (j - 1)) & 1u);
        const bool sp = (u >= 10.0);
        smask = (smask << 1) | (sp ? 1u : 0u);
        const unsigned long long bm = __ballot(sp);
        if (tid == 0) sbase[(size_t)(t0 + gg) * 32] = (uint32_t)bm;
      }
    } else if (tid >= 64) {
      for (int id = tid - 64; id < tvn * 32; id += 448) {
        const int r = id >> 5, nn = id & 31;
        S[((t0n + r) % RING3) * 32 + nn] = abase[(size_t)(t0n + r) * NHID + nn];
      }
    }
    __syncthreads();
  }
}

// ---------------------------------------------------------------------------
// K3: dense2 sparse gather from s1 u32 masks, W2 fp32 in LDS, f64 acc.
__global__ __launch_bounds__(256)
void k_dense2(const uint32_t* __restrict__ s1w,
              const float* __restrict__ W2, double* __restrict__ a2) {
  __shared__ float w2t[NHID * NOUT];  // 40 KB, [i][o]
  for (int k = threadIdx.x; k < NHID * NOUT; k += 256) {
    const int o = k >> 10, i = k & 1023;
    w2t[i * NOUT + o] = W2[k];
  }
  __syncthreads();
  const int col = blockIdx.x * 256 + threadIdx.x;  // 0..31999
  double acc[NOUT];
#pragma unroll
  for (int o = 0; o < NOUT; ++o) acc[o] = 0.0;
  const uint32_t* w = s1w + (size_t)col * 32;
  for (int wi = 0; wi < 32; ++wi) {
    uint32_t m = w[wi];
    const int ibase = wi * 32;
    while (m) {
      const int j = __ffs(m) - 1;
      m &= m - 1;
      const float* row = &w2t[(ibase + j) * NOUT];
#pragma unroll
      for (int o = 0; o < NOUT; ++o) acc[o] += (double)row[o];
    }
  }
  double* outp = a2 + (size_t)col * NOUT;
#pragma unroll
  for (int o = 0; o < NOUT; ++o) outp[o] = acc[o];
}

// ---------------------------------------------------------------------------
// K4: FUSED psp2 + spike2, one block per batch; whole [500][10] in LDS.
__global__ __launch_bounds__(256)
void k_l2(const double* __restrict__ a2, float* __restrict__ out) {
  __shared__ double S[T_SIM * NOUT];
  __shared__ double Y[T_SIM * NOUT];
  __shared__ double srm[KSRM];
  const int b = blockIdx.x, tid = threadIdx.x;
  if (tid < KSRM) srm[tid] = srm_tap(tid);
  for (int i = tid; i < T_SIM * NOUT; i += 256)
    S[i] = a2[(size_t)b * T_SIM * NOUT + i];
  __syncthreads();
  for (int i = tid; i < T_SIM * NOUT; i += 256) {
    const int t = i / 10, o = i - t * 10;
    const int kmax = (t < KSRM - 1) ? t : (KSRM - 1);
    double acc = 0.0;
    for (int k = 0; k <= kmax; ++k)
      acc += srm[k] * S[(t - k) * 10 + o];
    Y[i] = acc;
  }
  __syncthreads();
  if (tid < NOUT) {
    double refk[11];
#pragma unroll
    for (int j = 1; j <= 10; ++j) refk[j] = ref_tap(j);
    uint32_t smask = 0;
    float* op = out + ((size_t)b * NOUT + tid) * T_SIM;
    for (int t = 0; t < T_SIM; ++t) {
      double u = Y[t * 10 + tid];
#pragma unroll
      for (int j = 10; j >= 1; --j)
        u += refk[j] * (double)((smask >> (j - 1)) & 1u);
      const bool sp = (u >= 10.0);
      smask = (smask << 1) | (sp ? 1u : 0u);
      op[t] = sp ? 1.0f : 0.0f;
    }
  }
}

// ---------------------------------------------------------------------------
extern "C" void kernel_launch(void* const* d_in, const int* in_sizes, int n_in,
                              void* d_out, int out_size, void* d_ws, size_t ws_size,
                              hipStream_t stream) {
  const float* x  = (const float*)d_in[0];   // [64][1024][500]
  const float* W1 = (const float*)d_in[1];   // [1024][1024]
  const float* W2 = (const float*)d_in[2];   // [10][1024]
  float* out = (float*)d_out;                // [64][10][500]

  char* ws = (char*)d_ws;
  unsigned long long* bits1 = (unsigned long long*)(ws);   // 4,096,000
  float*  W1T = (float*) (ws + 4096000);                   // 4,194,304
  double* a1c = (double*)(ws + 8290304);                   // 131,072,000 (CHUNK=32)
  uint32_t* s1w = (uint32_t*)(ws + 139362304);             // 4,096,000
  double* a2  = (double*)(ws + 143458304);                 // 2,560,000
  // total ws use: 146,018,304 B

  hipLaunchKernelGGL(k_pack, dim3(NB, 16, 5), dim3(64), 0, stream, x, bits1);
  hipLaunchKernelGGL(k_transpose, dim3(16, 16), dim3(256), 0, stream, W1, W1T);

  for (int bc = 0; bc < NB; bc += CHUNK) {
    hipLaunchKernelGGL(k_dense1, dim3(CHUNK * T_SIM, 2), dim3(128), 0, stream,
                       (const uint32_t*)bits1, W1T, a1c, bc * T_SIM);
    hipLaunchKernelGGL(k_ps1, dim3(32, CHUNK), dim3(512), 0, stream,
                       a1c, s1w, bc);
  }

  hipLaunchKernelGGL(k_dense2, dim3(125), dim3(256), 0, stream, s1w, W2, a2);
  hipLaunchKernelGGL(k_l2, dim3(NB), dim3(256), 0, stream, a2, out);
}

// Round 7
// 935.418 us; speedup vs baseline: 1.2519x; 1.0823x over previous
//
#include <hip/hip_runtime.h>
#include <stdint.h>
#include <math.h>

#define T_SIM 500
#define NB    64
#define NIN   1024
#define NHID  1024
#define NOUT  10
#define KSRM  77     // SRM kernel taps 0..76 (srm[0] == 0)
#define CHUNK 32     // batches per chunk for layer-1 pipeline
#define TT5   12     // t-tile in fused psp+spike kernel
#define NT5   42     // ceil(500/12); last tile tv=8
#define RING5 128    // pow2 ring; needed span 76+2*12=100 <= 128

// Reference builds kernels in python f64 then rounds to fp32; we reproduce the
// exact fp32 tap values and do all accumulation in f64 (verified: absmax 0).
__device__ __forceinline__ double srm_tap(int k) {
  double u = (double)k / 10.0;
  double v = u * exp(1.0 - u);
  return (double)(float)v;
}
__device__ __forceinline__ double ref_tap(int j) {
  double v = (-20.0 * (double)j) * exp(1.0 - (double)j);
  return (double)(float)v;
}

// ---------------------------------------------------------------------------
// K0: pack binary input spikes x[b][i][t] (fp32 0/1) -> bits [b][t][16 x u64]
__global__ __launch_bounds__(64)
void k_pack(const float* __restrict__ x, unsigned long long* __restrict__ bits) {
  const int b = blockIdx.x, ig = blockIdx.y, tc = blockIdx.z;
  const int lane = threadIdx.x;
  const float* xr = x + ((size_t)b * NIN + ig * 64 + lane) * T_SIM;
  const int t0 = tc * 100;
  for (int t = t0; t < t0 + 100; t += 4) {
    const float4 v = *(const float4*)(xr + t);
    unsigned long long m0 = __ballot(v.x > 0.5f);
    unsigned long long m1 = __ballot(v.y > 0.5f);
    unsigned long long m2 = __ballot(v.z > 0.5f);
    unsigned long long m3 = __ballot(v.w > 0.5f);
    if (lane == 0) {
      unsigned long long* w = bits + (size_t)(b * T_SIM + t) * 16 + ig;
      w[0] = m0; w[16] = m1; w[32] = m2; w[48] = m3;
    }
  }
}

// ---------------------------------------------------------------------------
// K0b: W1[o][i] -> W1T[i][o] fp32, tiled 64x64 through LDS.
__global__ __launch_bounds__(256)
void k_transpose(const float* __restrict__ W1, float* __restrict__ W1T) {
  __shared__ float tile[64][65];
  const int bo = blockIdx.x * 64, bi = blockIdx.y * 64;
  for (int k = threadIdx.x; k < 4096; k += 256) {
    int r = k >> 6, c = k & 63;
    tile[r][c] = W1[(size_t)(bo + r) * NIN + bi + c];
  }
  __syncthreads();
  for (int k = threadIdx.x; k < 4096; k += 256) {
    int r = k >> 6, c = k & 63;
    W1T[(size_t)(bi + r) * NHID + bo + c] = tile[c][r];
  }
}

// ---------------------------------------------------------------------------
// K1: dense1 sparse gather v3: 8 loads in flight (double-buffered batch of 8),
// accumulator mapping (g&3) bitwise-identical to R6. Non-temporal a1c stores
// (no L2 allocate) so the 131MB write stream stops evicting W1T from L2.
// grid (CHUNK*500, 2), block 128.
__global__ __launch_bounds__(128)
void k_dense1(const uint32_t* __restrict__ bits, const float* __restrict__ W1T,
              double* __restrict__ a1c, int col_base) {
  __shared__ int list[NIN];
  __shared__ int nact_s;
  const int col_loc = blockIdx.x;
  const int tid = threadIdx.x;
  if (tid < 32) {
    uint32_t w = bits[(size_t)(col_base + col_loc) * 32 + tid];
    int c = __popc(w);
    int p = c;
#pragma unroll
    for (int d = 1; d < 32; d <<= 1) {
      int q = __shfl_up(p, d);
      if (tid >= d) p += q;
    }
    int excl = p - c;
    while (w) {
      const int j = __ffs(w) - 1;
      w &= w - 1;
      list[excl++] = tid * 32 + j;   // i ascending overall
    }
    if (tid == 31) nact_s = excl;
  }
  __syncthreads();
  const int n = nact_s;
  const int o = blockIdx.y * 512 + tid * 4;
  double ax[4] = {0,0,0,0}, ay[4] = {0,0,0,0};
  double az[4] = {0,0,0,0}, aw[4] = {0,0,0,0};
  float4 L[8];
  int g = 0;
  if (n >= 8) {
#pragma unroll
    for (int r = 0; r < 8; ++r)
      L[r] = *(const float4*)(W1T + (size_t)list[r] * NHID + o);
    for (g = 0; g + 16 <= n; g += 8) {
      float4 Nb[8];
#pragma unroll
      for (int r = 0; r < 8; ++r)
        Nb[r] = *(const float4*)(W1T + (size_t)list[g + 8 + r] * NHID + o);
#pragma unroll
      for (int r = 0; r < 8; ++r) {
        const int s = r & 3;   // (g+r)&3 == r&3 since g%8==0
        ax[s] += (double)L[r].x; ay[s] += (double)L[r].y;
        az[s] += (double)L[r].z; aw[s] += (double)L[r].w;
      }
#pragma unroll
      for (int r = 0; r < 8; ++r) L[r] = Nb[r];
    }
#pragma unroll
    for (int r = 0; r < 8; ++r) {
      const int s = r & 3;
      ax[s] += (double)L[r].x; ay[s] += (double)L[r].y;
      az[s] += (double)L[r].z; aw[s] += (double)L[r].w;
    }
    g += 8;
  }
  for (; g < n; ++g) {
    const float4 wv = *(const float4*)(W1T + (size_t)list[g] * NHID + o);
    const int s = g & 3;
    ax[s] += (double)wv.x; ay[s] += (double)wv.y;
    az[s] += (double)wv.z; aw[s] += (double)wv.w;
  }
  double* dst = a1c + (size_t)col_loc * NHID + o;
  __builtin_nontemporal_store((ax[0] + ax[1]) + (ax[2] + ax[3]), dst + 0);
  __builtin_nontemporal_store((ay[0] + ay[1]) + (ay[2] + ay[3]), dst + 1);
  __builtin_nontemporal_store((az[0] + az[1]) + (az[2] + az[3]), dst + 2);
  __builtin_nontemporal_store((aw[0] + aw[1]) + (aw[2] + aw[3]), dst + 3);
}

// ---------------------------------------------------------------------------
// K2: FUSED psp1 + spike1 v5. 448 thr = 384 FIR (4 tap-groups x 3 t-quads x
// 32 n, TT=12) + 1 scan wave that scans tile k-1 CONCURRENTLY with FIR(k).
// Ring = 128 rows (pow2 slot math); each FIR thread prefetches 1 element of
// tile k+1 under the FIR. One barrier per tile. Partials + scan arithmetic
// bitwise-identical to R6. grid (32, CHUNK).
// LDS: 128*32*8 + 2*4*12*32*8 + 80*8 = 57,984 B -> 2 blocks/CU.
__global__ __launch_bounds__(448)
void k_ps1(const double* __restrict__ a1c, uint32_t* __restrict__ s1w,
           int b_base) {
  __shared__ double S[RING5 * 32];
  __shared__ double Yp[2][4][TT5 * 32];
  __shared__ double TB[80];     // srm[0..76], zero-padded to 80
  const int ng = blockIdx.x, b_loc = blockIdx.y;
  const int tid = threadIdx.x;
  const double* __restrict__ abase = a1c + (size_t)b_loc * T_SIM * NHID + ng * 32;
  uint32_t* __restrict__ sbase = s1w + (size_t)(b_base + b_loc) * T_SIM * 32 + ng;

  if (tid < 80) TB[tid] = (tid <= 76) ? srm_tap(tid) : 0.0;
  for (int i = tid; i < RING5 * 32; i += 448) S[i] = 0.0;
  __syncthreads();
  for (int id = tid; id < TT5 * 32; id += 448) {   // tile 0 -> slots 0..11
    const int r = id >> 5, nn = id & 31;
    S[r * 32 + nn] = abase[(size_t)r * NHID + nn];
  }

  const bool isFIR = (tid < 384);
  const int g   = tid / 96;          // tap group 0..3 (FIR threads)
  const int rem = tid - g * 96;
  const int q   = rem >> 5;          // t-quad 0..2
  const int n   = rem & 31;          // neuron
  double tap[20];
  __syncthreads();                   // TB + tile0 visible
  if (isFIR) {
#pragma unroll
    for (int j = 0; j < 20; ++j) tap[j] = TB[20 * g + j];
  }
  double refk[11];
#pragma unroll
  for (int j = 1; j <= 10; ++j) refk[j] = ref_tap(j);
  uint32_t smask = 0;

  for (int k = 0; k < NT5; ++k) {
    const int t0 = k * TT5;
    const int tv = (T_SIM - t0 < TT5) ? (T_SIM - t0) : TT5;
    const int t0n = t0 + TT5;
    const int tvn = (t0n >= T_SIM) ? 0 : ((T_SIM - t0n < TT5) ? (T_SIM - t0n) : TT5);
    if (isFIR) {
      // ---- prefetch 1 element of tile k+1 (completes under the FIR) ----
      double pf = 0.0;
      const int pr = tid >> 5, pn = tid & 31;
      const bool hasPf = (tid < tvn * 32);
      if (hasPf) pf = abase[(size_t)(t0n + pr) * NHID + pn];
      // ---- partial FIR: outputs tb..tb+3, taps 20g..20g+19 ----
      const int tb = t0 + q * 4;
      int slot = (tb - 20 * g - 19 + 1024) & (RING5 - 1);
      double a0 = 0, a1 = 0, a2 = 0, a3 = 0;
#pragma unroll
      for (int s = 0; s < 23; ++s) {
        const double v = S[slot * 32 + n];
        slot = (slot + 1) & (RING5 - 1);
        if (s <= 19)           a0 += tap[19 - s] * v;
        if (s >= 1 && s <= 20) a1 += tap[20 - s] * v;
        if (s >= 2 && s <= 21) a2 += tap[21 - s] * v;
        if (s >= 3)            a3 += tap[22 - s] * v;
      }
      double* Yk = Yp[k & 1][g];
      const int tl = q * 4;
      if (tl + 0 < tv) Yk[(tl + 0) * 32 + n] = a0;
      if (tl + 1 < tv) Yk[(tl + 1) * 32 + n] = a1;
      if (tl + 2 < tv) Yk[(tl + 2) * 32 + n] = a2;
      if (tl + 3 < tv) Yk[(tl + 3) * 32 + n] = a3;
      // ---- write prefetched row into ring (slots disjoint from window k) ----
      if (hasPf) S[((t0n + pr) & (RING5 - 1)) * 32 + pn] = pf;
    } else if (k > 0) {
      // ---- scan wave: refractory scan of tile k-1 (tv always 12 there) ----
      const int lane = tid - 384;
      if (lane < 32) {
        const int t0p = t0 - TT5;
        const double* Y0 = Yp[(k - 1) & 1][0];
        const double* Y1 = Yp[(k - 1) & 1][1];
        const double* Y2 = Yp[(k - 1) & 1][2];
        const double* Y3 = Yp[(k - 1) & 1][3];
        for (int gg = 0; gg < TT5; ++gg) {
          double u = (Y0[gg * 32 + lane] + Y1[gg * 32 + lane]) +
                     (Y2[gg * 32 + lane] + Y3[gg * 32 + lane]);
#pragma unroll
          for (int j = 10; j >= 1; --j)
            u += refk[j] * (double)((smask >> (j - 1)) & 1u);
          const bool sp = (u >= 10.0);
          smask = (smask << 1) | (sp ? 1u : 0u);
          const unsigned long long bm = __ballot(sp);
          if (lane == 0) sbase[(size_t)(t0p + gg) * 32] = (uint32_t)bm;
        }
      }
    }
    __syncthreads();
  }
  // ---- epilogue: scan last tile (t0p = 492, tv = 8) ----
  if (!isFIR) {
    const int lane = tid - 384;
    if (lane < 32) {
      const int t0p = (NT5 - 1) * TT5;
      const int tvp = T_SIM - t0p;
      const double* Y0 = Yp[(NT5 - 1) & 1][0];
      const double* Y1 = Yp[(NT5 - 1) & 1][1];
      const double* Y2 = Yp[(NT5 - 1) & 1][2];
      const double* Y3 = Yp[(NT5 - 1) & 1][3];
      for (int gg = 0; gg < tvp; ++gg) {
        double u = (Y0[gg * 32 + lane] + Y1[gg * 32 + lane]) +
                   (Y2[gg * 32 + lane] + Y3[gg * 32 + lane]);
#pragma unroll
        for (int j = 10; j >= 1; --j)
          u += refk[j] * (double)((smask >> (j - 1)) & 1u);
        const bool sp = (u >= 10.0);
        smask = (smask << 1) | (sp ? 1u : 0u);
        const unsigned long long bm = __ballot(sp);
        if (lane == 0) sbase[(size_t)(t0p + gg) * 32] = (uint32_t)bm;
      }
    }
  }
}

// ---------------------------------------------------------------------------
// K3: dense2 sparse gather from s1 u32 masks, W2 fp32 in LDS, f64 acc.
__global__ __launch_bounds__(256)
void k_dense2(const uint32_t* __restrict__ s1w,
              const float* __restrict__ W2, double* __restrict__ a2) {
  __shared__ float w2t[NHID * NOUT];  // 40 KB, [i][o]
  for (int k = threadIdx.x; k < NHID * NOUT; k += 256) {
    const int o = k >> 10, i = k & 1023;
    w2t[i * NOUT + o] = W2[k];
  }
  __syncthreads();
  const int col = blockIdx.x * 256 + threadIdx.x;  // 0..31999
  double acc[NOUT];
#pragma unroll
  for (int o = 0; o < NOUT; ++o) acc[o] = 0.0;
  const uint32_t* w = s1w + (size_t)col * 32;
  for (int wi = 0; wi < 32; ++wi) {
    uint32_t m = w[wi];
    const int ibase = wi * 32;
    while (m) {
      const int j = __ffs(m) - 1;
      m &= m - 1;
      const float* row = &w2t[(ibase + j) * NOUT];
#pragma unroll
      for (int o = 0; o < NOUT; ++o) acc[o] += (double)row[o];
    }
  }
  double* outp = a2 + (size_t)col * NOUT;
#pragma unroll
  for (int o = 0; o < NOUT; ++o) outp[o] = acc[o];
}

// ---------------------------------------------------------------------------
// K4: FUSED psp2 + spike2, one block per batch; whole [500][10] in LDS.
__global__ __launch_bounds__(256)
void k_l2(const double* __restrict__ a2, float* __restrict__ out) {
  __shared__ double S[T_SIM * NOUT];
  __shared__ double Y[T_SIM * NOUT];
  __shared__ double srm[KSRM];
  const int b = blockIdx.x, tid = threadIdx.x;
  if (tid < KSRM) srm[tid] = srm_tap(tid);
  for (int i = tid; i < T_SIM * NOUT; i += 256)
    S[i] = a2[(size_t)b * T_SIM * NOUT + i];
  __syncthreads();
  for (int i = tid; i < T_SIM * NOUT; i += 256) {
    const int t = i / 10, o = i - t * 10;
    const int kmax = (t < KSRM - 1) ? t : (KSRM - 1);
    double acc = 0.0;
    for (int k = 0; k <= kmax; ++k)
      acc += srm[k] * S[(t - k) * 10 + o];
    Y[i] = acc;
  }
  __syncthreads();
  if (tid < NOUT) {
    double refk[11];
#pragma unroll
    for (int j = 1; j <= 10; ++j) refk[j] = ref_tap(j);
    uint32_t smask = 0;
    float* op = out + ((size_t)b * NOUT + tid) * T_SIM;
    for (int t = 0; t < T_SIM; ++t) {
      double u = Y[t * 10 + tid];
#pragma unroll
      for (int j = 10; j >= 1; --j)
        u += refk[j] * (double)((smask >> (j - 1)) & 1u);
      const bool sp = (u >= 10.0);
      smask = (smask << 1) | (sp ? 1u : 0u);
      op[t] = sp ? 1.0f : 0.0f;
    }
  }
}

// ---------------------------------------------------------------------------
extern "C" void kernel_launch(void* const* d_in, const int* in_sizes, int n_in,
                              void* d_out, int out_size, void* d_ws, size_t ws_size,
                              hipStream_t stream) {
  const float* x  = (const float*)d_in[0];   // [64][1024][500]
  const float* W1 = (const float*)d_in[1];   // [1024][1024]
  const float* W2 = (const float*)d_in[2];   // [10][1024]
  float* out = (float*)d_out;                // [64][10][500]

  char* ws = (char*)d_ws;
  unsigned long long* bits1 = (unsigned long long*)(ws);   // 4,096,000
  float*  W1T = (float*) (ws + 4096000);                   // 4,194,304
  double* a1c = (double*)(ws + 8290304);                   // 131,072,000 (CHUNK=32)
  uint32_t* s1w = (uint32_t*)(ws + 139362304);             // 4,096,000
  double* a2  = (double*)(ws + 143458304);                 // 2,560,000
  // total ws use: 146,018,304 B

  hipLaunchKernelGGL(k_pack, dim3(NB, 16, 5), dim3(64), 0, stream, x, bits1);
  hipLaunchKernelGGL(k_transpose, dim3(16, 16), dim3(256), 0, stream, W1, W1T);

  for (int bc = 0; bc < NB; bc += CHUNK) {
    hipLaunchKernelGGL(k_dense1, dim3(CHUNK * T_SIM, 2), dim3(128), 0, stream,
                       (const uint32_t*)bits1, W1T, a1c, bc * T_SIM);
    hipLaunchKernelGGL(k_ps1, dim3(32, CHUNK), dim3(448), 0, stream,
                       a1c, s1w, bc);
  }

  hipLaunchKernelGGL(k_dense2, dim3(125), dim3(256), 0, stream, s1w, W2, a2);
  hipLaunchKernelGGL(k_l2, dim3(NB), dim3(256), 0, stream, a2, out);
}